// Round 1
// baseline (2152.228 us; speedup 1.0000x reference)
//
#include <hip/hip_runtime.h>
#include <math.h>

#define C_    256
#define NH    8
#define HD_   32
#define NG    32
#define CPG   8
#define NPIX  4096
#define BATCH 2
#define EPSV  1e-5f
#define TJ    32   // attention key-tile

// ---------------------------------------------------------------------------
// Kernel 1: GroupNorm statistics. One block per (batch, group).
// ---------------------------------------------------------------------------
__global__ __launch_bounds__(256) void gn_stats_kernel(const float* __restrict__ x,
                                                       float* __restrict__ stats) {
    const int blk = blockIdx.x;
    const int b = blk >> 5, g = blk & 31;
    const float* __restrict__ xp = x + ((size_t)(b * C_ + g * CPG)) * NPIX;

    float s = 0.f, ss = 0.f;
    for (int i = threadIdx.x * 4; i < CPG * NPIX; i += 256 * 4) {
        const float4 v = *(const float4*)(xp + i);
        s  += v.x + v.y + v.z + v.w;
        ss += v.x * v.x + v.y * v.y + v.z * v.z + v.w * v.w;
    }
    // wave (64-lane) reduce
    #pragma unroll
    for (int off = 32; off; off >>= 1) {
        s  += __shfl_down(s, off);
        ss += __shfl_down(ss, off);
    }
    __shared__ float ls[4], lss[4];
    const int wid = threadIdx.x >> 6, lane = threadIdx.x & 63;
    if (lane == 0) { ls[wid] = s; lss[wid] = ss; }
    __syncthreads();
    if (threadIdx.x == 0) {
        float S = 0.f, SS = 0.f;
        #pragma unroll
        for (int w = 0; w < 4; ++w) { S += ls[w]; SS += lss[w]; }
        const float inv_n = 1.0f / (float)(CPG * NPIX);
        const float mean = S * inv_n;
        const float var  = SS * inv_n - mean * mean;
        stats[blk * 2 + 0] = mean;
        stats[blk * 2 + 1] = rsqrtf(var + EPSV);
    }
}

// ---------------------------------------------------------------------------
// Kernel 2/4: tiled fp32 GEMM  out[b, m, n] = sum_c W[m,c] * src[b,c,n] + bias
// MODE 0: src = x with GroupNorm applied on-the-fly (QKV projection, M=768)
// MODE 1: src = attention output; adds residual x (proj, M=256)
// Block: 256 threads, 64x64 output tile, BK=16, 4x4 micro-tile per thread.
// ---------------------------------------------------------------------------
template <int MODE>
__global__ __launch_bounds__(256) void gemm_kernel(const float* __restrict__ W,
                                                   const float* __restrict__ bias,
                                                   const float* __restrict__ src,
                                                   const float* __restrict__ stats,
                                                   const float* __restrict__ gamma,
                                                   const float* __restrict__ beta,
                                                   const float* __restrict__ resid,
                                                   float* __restrict__ out) {
    constexpr int M = (MODE == 0) ? 768 : 256;
    __shared__ float As[16][64];
    __shared__ float Bs[16][64];

    const int b  = blockIdx.z;
    const int n0 = blockIdx.x * 64;
    const int m0 = blockIdx.y * 64;
    const int tid = threadIdx.x;
    const int tx = tid & 15, ty = tid >> 4;

    const float* __restrict__ srcb = src + (size_t)b * C_ * NPIX;

    float acc[4][4];
    #pragma unroll
    for (int i = 0; i < 4; ++i)
        #pragma unroll
        for (int j = 0; j < 4; ++j) acc[i][j] = 0.f;

    for (int k0 = 0; k0 < C_; k0 += 16) {
        // ---- stage A tile (64 m x 16 k), transposed store to As[k][m]
        {
            const int m  = tid >> 2;
            const int kk = (tid & 3) << 2;
            const float4 av = *(const float4*)(W + (size_t)(m0 + m) * C_ + k0 + kk);
            As[kk + 0][m] = av.x;
            As[kk + 1][m] = av.y;
            As[kk + 2][m] = av.z;
            As[kk + 3][m] = av.w;
        }
        // ---- stage B tile (16 k x 64 n), GN applied for MODE 0
        {
            const int kk = tid >> 4;
            const int nn = (tid & 15) << 2;
            const int c  = k0 + kk;
            float4 bv = *(const float4*)(srcb + (size_t)c * NPIX + n0 + nn);
            if (MODE == 0) {
                const int g = c >> 3;
                const float mean = stats[(b * NG + g) * 2 + 0];
                const float rstd = stats[(b * NG + g) * 2 + 1];
                const float ga = gamma[c] * rstd;
                const float be = beta[c] - mean * ga;
                bv.x = bv.x * ga + be;
                bv.y = bv.y * ga + be;
                bv.z = bv.z * ga + be;
                bv.w = bv.w * ga + be;
            }
            *(float4*)&Bs[kk][nn] = bv;
        }
        __syncthreads();
        #pragma unroll
        for (int k = 0; k < 16; ++k) {
            const float4 a  = *(const float4*)(&As[k][ty << 2]);
            const float4 bb = *(const float4*)(&Bs[k][tx << 2]);
            const float av[4] = {a.x, a.y, a.z, a.w};
            const float bv[4] = {bb.x, bb.y, bb.z, bb.w};
            #pragma unroll
            for (int i = 0; i < 4; ++i)
                #pragma unroll
                for (int j = 0; j < 4; ++j)
                    acc[i][j] = fmaf(av[i], bv[j], acc[i][j]);
        }
        __syncthreads();
    }

    // ---- epilogue
    #pragma unroll
    for (int i = 0; i < 4; ++i) {
        const int m = m0 + (ty << 2) + i;
        const int n = n0 + (tx << 2);
        const float bs = bias[m];
        float4 r;
        r.x = acc[i][0] + bs;
        r.y = acc[i][1] + bs;
        r.z = acc[i][2] + bs;
        r.w = acc[i][3] + bs;
        if (MODE == 1) {
            const float4 rx = *(const float4*)(resid + ((size_t)b * C_ + m) * NPIX + n);
            r.x += rx.x; r.y += rx.y; r.z += rx.z; r.w += rx.w;
        }
        *(float4*)(out + ((size_t)b * M + m) * NPIX + n) = r;
    }
}

// ---------------------------------------------------------------------------
// Kernel 3: attention. One thread per query row; flash-style online softmax.
// qkv layout: (B, 768, NPIX) channel-major; channel = {0:Q,256:K,512:V} + h*32+d
// K/V tiles staged in LDS [d][j] (padded), read uniform (broadcast, no conflict)
// ---------------------------------------------------------------------------
__global__ __launch_bounds__(256) void attn_kernel(const float* __restrict__ qkv,
                                                   float* __restrict__ ao) {
    __shared__ float Ks[HD_][TJ + 8];
    __shared__ float Vs[HD_][TJ + 8];

    const int b = blockIdx.z, h = blockIdx.y;
    const int qi = blockIdx.x * 256 + threadIdx.x;
    const float* __restrict__ qb = qkv + ((size_t)b * 768 + h * HD_) * NPIX;
    const float* __restrict__ kb = qkv + ((size_t)b * 768 + 256 + h * HD_) * NPIX;
    const float* __restrict__ vb = qkv + ((size_t)b * 768 + 512 + h * HD_) * NPIX;

    const float scale = 0.17677669529663687f;  // 1/sqrt(32)
    float q[HD_], acc[HD_];
    #pragma unroll
    for (int d = 0; d < HD_; ++d) {
        q[d] = qb[(size_t)d * NPIX + qi] * scale;
        acc[d] = 0.f;
    }
    float m = -3.0e38f, l = 0.f;

    const int sd = threadIdx.x >> 3;        // 0..31 : d row to stage
    const int sj = (threadIdx.x & 7) << 2;  // 0..28 : j offset (float4)

    for (int j0 = 0; j0 < NPIX; j0 += TJ) {
        const float4 kv4 = *(const float4*)(kb + (size_t)sd * NPIX + j0 + sj);
        const float4 vv4 = *(const float4*)(vb + (size_t)sd * NPIX + j0 + sj);
        __syncthreads();  // previous tile's compute done
        *(float4*)&Ks[sd][sj] = kv4;
        *(float4*)&Vs[sd][sj] = vv4;
        __syncthreads();  // staging visible

        float s[TJ];
        #pragma unroll
        for (int j = 0; j < TJ; ++j) s[j] = 0.f;
        #pragma unroll
        for (int d = 0; d < HD_; ++d) {
            const float qd = q[d];
            const float4* kr = (const float4*)(&Ks[d][0]);
            #pragma unroll
            for (int j4 = 0; j4 < TJ / 4; ++j4) {
                const float4 kk = kr[j4];
                s[4 * j4 + 0] = fmaf(qd, kk.x, s[4 * j4 + 0]);
                s[4 * j4 + 1] = fmaf(qd, kk.y, s[4 * j4 + 1]);
                s[4 * j4 + 2] = fmaf(qd, kk.z, s[4 * j4 + 2]);
                s[4 * j4 + 3] = fmaf(qd, kk.w, s[4 * j4 + 3]);
            }
        }
        float tm = s[0];
        #pragma unroll
        for (int j = 1; j < TJ; ++j) tm = fmaxf(tm, s[j]);
        const float mn = fmaxf(m, tm);
        const float cf = __expf(m - mn);
        float ls = 0.f;
        #pragma unroll
        for (int j = 0; j < TJ; ++j) {
            s[j] = __expf(s[j] - mn);
            ls += s[j];
        }
        l = l * cf + ls;
        m = mn;
        #pragma unroll
        for (int d = 0; d < HD_; ++d) {
            float a = acc[d] * cf;
            const float4* vr = (const float4*)(&Vs[d][0]);
            #pragma unroll
            for (int j4 = 0; j4 < TJ / 4; ++j4) {
                const float4 vv = vr[j4];
                a = fmaf(s[4 * j4 + 0], vv.x, a);
                a = fmaf(s[4 * j4 + 1], vv.y, a);
                a = fmaf(s[4 * j4 + 2], vv.z, a);
                a = fmaf(s[4 * j4 + 3], vv.w, a);
            }
            acc[d] = a;
        }
    }

    const float inv = 1.f / l;
    #pragma unroll
    for (int d = 0; d < HD_; ++d)
        ao[((size_t)b * C_ + h * HD_ + d) * NPIX + qi] = acc[d] * inv;
}

// ---------------------------------------------------------------------------
extern "C" void kernel_launch(void* const* d_in, const int* in_sizes, int n_in,
                              void* d_out, int out_size, void* d_ws, size_t ws_size,
                              hipStream_t stream) {
    (void)in_sizes; (void)n_in; (void)out_size; (void)ws_size;
    const float* x      = (const float*)d_in[0];
    const float* gamma  = (const float*)d_in[1];
    const float* beta   = (const float*)d_in[2];
    const float* qkv_w  = (const float*)d_in[3];
    const float* qkv_b  = (const float*)d_in[4];
    const float* proj_w = (const float*)d_in[5];
    const float* proj_b = (const float*)d_in[6];
    float* out = (float*)d_out;

    char* ws = (char*)d_ws;
    float* qkv   = (float*)ws;                                   // B*768*NPIX f32 = 24 MB
    float* ao    = (float*)(ws + (size_t)BATCH * 768 * NPIX * 4);  // B*256*NPIX f32 = 8 MB
    float* stats = (float*)(ws + (size_t)BATCH * 768 * NPIX * 4 +
                                 (size_t)BATCH * C_ * NPIX * 4);   // 64*2 f32

    gn_stats_kernel<<<dim3(BATCH * NG), dim3(256), 0, stream>>>(x, stats);
    gemm_kernel<0><<<dim3(NPIX / 64, 768 / 64, BATCH), dim3(256), 0, stream>>>(
        qkv_w, qkv_b, x, stats, gamma, beta, nullptr, qkv);
    attn_kernel<<<dim3(NPIX / 256, NH, BATCH), dim3(256), 0, stream>>>(qkv, ao);
    gemm_kernel<1><<<dim3(NPIX / 64, 256 / 64, BATCH), dim3(256), 0, stream>>>(
        proj_w, proj_b, ao, nullptr, nullptr, nullptr, x, out);
}

// Round 2
// 366.836 us; speedup vs baseline: 5.8670x; 5.8670x over previous
//
#include <hip/hip_runtime.h>
#include <math.h>

#define C_    256
#define NH    8
#define HD_   32
#define NG    32
#define CPG   8
#define NPIX  4096
#define BATCH 2
#define EPSV  1e-5f

typedef __bf16 bf16x8 __attribute__((ext_vector_type(8)));
typedef __bf16 bf16x4 __attribute__((ext_vector_type(4)));
typedef float  f32x4  __attribute__((ext_vector_type(4)));

// ---------------------------------------------------------------------------
// Kernel 1: GroupNorm statistics. One block per (batch, group).
// ---------------------------------------------------------------------------
__global__ __launch_bounds__(256) void gn_stats_kernel(const float* __restrict__ x,
                                                       float* __restrict__ stats) {
    const int blk = blockIdx.x;
    const int b = blk >> 5, g = blk & 31;
    const float* __restrict__ xp = x + ((size_t)(b * C_ + g * CPG)) * NPIX;

    float s = 0.f, ss = 0.f;
    for (int i = threadIdx.x * 4; i < CPG * NPIX; i += 256 * 4) {
        const float4 v = *(const float4*)(xp + i);
        s  += v.x + v.y + v.z + v.w;
        ss += v.x * v.x + v.y * v.y + v.z * v.z + v.w * v.w;
    }
    #pragma unroll
    for (int off = 32; off; off >>= 1) {
        s  += __shfl_down(s, off);
        ss += __shfl_down(ss, off);
    }
    __shared__ float ls[4], lss[4];
    const int wid = threadIdx.x >> 6, lane = threadIdx.x & 63;
    if (lane == 0) { ls[wid] = s; lss[wid] = ss; }
    __syncthreads();
    if (threadIdx.x == 0) {
        float S = 0.f, SS = 0.f;
        #pragma unroll
        for (int w = 0; w < 4; ++w) { S += ls[w]; SS += lss[w]; }
        const float inv_n = 1.0f / (float)(CPG * NPIX);
        const float mean = S * inv_n;
        const float var  = SS * inv_n - mean * mean;
        stats[blk * 2 + 0] = mean;
        stats[blk * 2 + 1] = rsqrtf(var + EPSV);
    }
}

// ---------------------------------------------------------------------------
// Kernel 2/5: tiled fp32 GEMM  out[b, m, n] = sum_c W[m,c] * src[b,c,n] + bias
// MODE 0: src = x with GroupNorm on-the-fly (QKV, M=768), OUTPUT bf16
// MODE 1: src = attention out fp32; adds residual x (proj, M=256), OUTPUT f32
// ---------------------------------------------------------------------------
template <int MODE>
__global__ __launch_bounds__(256) void gemm_kernel(const float* __restrict__ W,
                                                   const float* __restrict__ bias,
                                                   const float* __restrict__ src,
                                                   const float* __restrict__ stats,
                                                   const float* __restrict__ gamma,
                                                   const float* __restrict__ beta,
                                                   const float* __restrict__ resid,
                                                   float* __restrict__ out,
                                                   __bf16* __restrict__ outb) {
    constexpr int M = (MODE == 0) ? 768 : 256;
    __shared__ float As[16][64];
    __shared__ float Bs[16][64];

    const int b  = blockIdx.z;
    const int n0 = blockIdx.x * 64;
    const int m0 = blockIdx.y * 64;
    const int tid = threadIdx.x;
    const int tx = tid & 15, ty = tid >> 4;

    const float* __restrict__ srcb = src + (size_t)b * C_ * NPIX;

    float acc[4][4];
    #pragma unroll
    for (int i = 0; i < 4; ++i)
        #pragma unroll
        for (int j = 0; j < 4; ++j) acc[i][j] = 0.f;

    for (int k0 = 0; k0 < C_; k0 += 16) {
        {
            const int m  = tid >> 2;
            const int kk = (tid & 3) << 2;
            const float4 av = *(const float4*)(W + (size_t)(m0 + m) * C_ + k0 + kk);
            As[kk + 0][m] = av.x;
            As[kk + 1][m] = av.y;
            As[kk + 2][m] = av.z;
            As[kk + 3][m] = av.w;
        }
        {
            const int kk = tid >> 4;
            const int nn = (tid & 15) << 2;
            const int c  = k0 + kk;
            float4 bv = *(const float4*)(srcb + (size_t)c * NPIX + n0 + nn);
            if (MODE == 0) {
                const int g = c >> 3;
                const float mean = stats[(b * NG + g) * 2 + 0];
                const float rstd = stats[(b * NG + g) * 2 + 1];
                const float ga = gamma[c] * rstd;
                const float be = beta[c] - mean * ga;
                bv.x = bv.x * ga + be;
                bv.y = bv.y * ga + be;
                bv.z = bv.z * ga + be;
                bv.w = bv.w * ga + be;
            }
            *(float4*)&Bs[kk][nn] = bv;
        }
        __syncthreads();
        #pragma unroll
        for (int k = 0; k < 16; ++k) {
            const float4 a  = *(const float4*)(&As[k][ty << 2]);
            const float4 bb = *(const float4*)(&Bs[k][tx << 2]);
            const float av[4] = {a.x, a.y, a.z, a.w};
            const float bv[4] = {bb.x, bb.y, bb.z, bb.w};
            #pragma unroll
            for (int i = 0; i < 4; ++i)
                #pragma unroll
                for (int j = 0; j < 4; ++j)
                    acc[i][j] = fmaf(av[i], bv[j], acc[i][j]);
        }
        __syncthreads();
    }

    #pragma unroll
    for (int i = 0; i < 4; ++i) {
        const int m = m0 + (ty << 2) + i;
        const int n = n0 + (tx << 2);
        const float bs = bias[m];
        float4 r;
        r.x = acc[i][0] + bs;
        r.y = acc[i][1] + bs;
        r.z = acc[i][2] + bs;
        r.w = acc[i][3] + bs;
        if (MODE == 1) {
            const float4 rx = *(const float4*)(resid + ((size_t)b * C_ + m) * NPIX + n);
            r.x += rx.x; r.y += rx.y; r.z += rx.z; r.w += rx.w;
            *(float4*)(out + ((size_t)b * M + m) * NPIX + n) = r;
        } else {
            bf16x4 ob;
            ob[0] = (__bf16)r.x; ob[1] = (__bf16)r.y;
            ob[2] = (__bf16)r.z; ob[3] = (__bf16)r.w;
            *(bf16x4*)(outb + ((size_t)b * M + m) * NPIX + n) = ob;
        }
    }
}

// ---------------------------------------------------------------------------
// Kernel 3: repack. Transpose Q (pre-scaled 1/sqrt(hd)) and K from bf16
// (b, ch, n) into [bh][n][d] bf16 fragment-friendly layout.
// ---------------------------------------------------------------------------
__global__ __launch_bounds__(256) void repack_kernel(const __bf16* __restrict__ qkvb,
                                                     __bf16* __restrict__ Qb,
                                                     __bf16* __restrict__ Kb) {
    const int b = blockIdx.z, h = blockIdx.y, n0 = blockIdx.x * 64;
    const int t = threadIdx.x;
    const int d = t >> 3, nn = (t & 7) * 8;
    const int bh = b * NH + h;
    __shared__ __align__(16) __bf16 tile[2][64][48];
    const float scale = 0.17677669529663687f;  // 1/sqrt(32)
    {
        bf16x8 v = *(const bf16x8*)(qkvb + ((size_t)b * 768 + h * HD_ + d) * NPIX + n0 + nn);
        #pragma unroll
        for (int i = 0; i < 8; ++i) tile[0][nn + i][d] = (__bf16)((float)v[i] * scale);
    }
    {
        bf16x8 v = *(const bf16x8*)(qkvb + ((size_t)b * 768 + 256 + h * HD_ + d) * NPIX + n0 + nn);
        #pragma unroll
        for (int i = 0; i < 8; ++i) tile[1][nn + i][d] = v[i];
    }
    __syncthreads();
    const int n = t >> 2, seg = (t & 3) * 8;
    *(bf16x8*)(Qb + ((size_t)bh * NPIX + n0 + n) * HD_ + seg) = *(const bf16x8*)(&tile[0][n][seg]);
    *(bf16x8*)(Kb + ((size_t)bh * NPIX + n0 + n) * HD_ + seg) = *(const bf16x8*)(&tile[1][n][seg]);
}

// ---------------------------------------------------------------------------
// Kernel 4: MFMA flash attention. One wave = 16 queries; swapped QK^T
// (S^T = mfma(K,Q)) so softmax is 8 in-register values + shfl_xor(16,32);
// P^T feeds PV mfma directly (A/B slot k-maps agree, HW permutation cancels).
// No LDS, no barriers; K/V served from L2 (256 KB/head).
// ---------------------------------------------------------------------------
__global__ __launch_bounds__(256) void attn_mfma_kernel(const __bf16* __restrict__ Qb,
                                                        const __bf16* __restrict__ Kb,
                                                        const __bf16* __restrict__ qkvb,
                                                        float* __restrict__ ao) {
    const int b = blockIdx.z, h = blockIdx.y;
    const int wave = threadIdx.x >> 6;
    const int lane = threadIdx.x & 63;
    const int q0 = blockIdx.x * 64 + wave * 16;
    const int bh = b * NH + h;
    const int col = lane & 15;     // query col (B n-index) / d (A m-index for V)
    const int grp = lane >> 4;     // 0..3

    const __bf16* qp = Qb + ((size_t)bh * NPIX + q0) * HD_;
    const __bf16* kp = Kb + (size_t)bh * NPIX * HD_;
    const __bf16* vp = qkvb + ((size_t)b * 768 + 512 + h * HD_) * NPIX;  // [d][n]

    const bf16x8 fq = *(const bf16x8*)(qp + col * HD_ + grp * 8);

    f32x4 acc0 = {0.f, 0.f, 0.f, 0.f}, acc1 = {0.f, 0.f, 0.f, 0.f};
    float m = -3.0e38f, l = 0.f;

    for (int k0 = 0; k0 < NPIX; k0 += 32) {
        const __bf16* kt = kp + (size_t)k0 * HD_;
        const bf16x8 fk0 = *(const bf16x8*)(kt + col * HD_ + grp * 8);
        const bf16x8 fk1 = *(const bf16x8*)(kt + (16 + col) * HD_ + grp * 8);
        f32x4 z = {0.f, 0.f, 0.f, 0.f};
        f32x4 s0 = __builtin_amdgcn_mfma_f32_16x16x32_bf16(fk0, fq, z, 0, 0, 0);
        f32x4 s1 = __builtin_amdgcn_mfma_f32_16x16x32_bf16(fk1, fq, z, 0, 0, 0);
        // lane holds S^T[key = k0+4*grp+r][query q0+col] in s0[r]; +16 in s1[r]

        float pmax = fmaxf(fmaxf(fmaxf(s0[0], s0[1]), fmaxf(s0[2], s0[3])),
                           fmaxf(fmaxf(s1[0], s1[1]), fmaxf(s1[2], s1[3])));
        pmax = fmaxf(pmax, __shfl_xor(pmax, 16));
        pmax = fmaxf(pmax, __shfl_xor(pmax, 32));
        const float mn = fmaxf(m, pmax);
        const float cf = __expf(m - mn);
        float p[8];
        float ls = 0.f;
        #pragma unroll
        for (int r = 0; r < 4; ++r) { p[r] = __expf(s0[r] - mn); ls += p[r]; }
        #pragma unroll
        for (int r = 0; r < 4; ++r) { p[4 + r] = __expf(s1[r] - mn); ls += p[4 + r]; }
        ls += __shfl_xor(ls, 16);
        ls += __shfl_xor(ls, 32);
        l = l * cf + ls;
        m = mn;

        bf16x8 fp_;
        #pragma unroll
        for (int j = 0; j < 8; ++j) fp_[j] = (__bf16)p[j];

        // V fragments: slot j<4 -> key k0+4g+j ; j>=4 -> key k0+16+4g+(j-4)
        const __bf16* vt0 = vp + (size_t)col * NPIX + k0 + 4 * grp;
        const __bf16* vt1 = vp + (size_t)(16 + col) * NPIX + k0 + 4 * grp;
        const bf16x4 a0 = *(const bf16x4*)(vt0);
        const bf16x4 a1 = *(const bf16x4*)(vt0 + 16);
        const bf16x4 b0 = *(const bf16x4*)(vt1);
        const bf16x4 b1 = *(const bf16x4*)(vt1 + 16);
        bf16x8 fv0, fv1;
        #pragma unroll
        for (int j = 0; j < 4; ++j) {
            fv0[j] = a0[j]; fv0[4 + j] = a1[j];
            fv1[j] = b0[j]; fv1[4 + j] = b1[j];
        }
        #pragma unroll
        for (int r = 0; r < 4; ++r) { acc0[r] *= cf; acc1[r] *= cf; }
        acc0 = __builtin_amdgcn_mfma_f32_16x16x32_bf16(fv0, fp_, acc0, 0, 0, 0);
        acc1 = __builtin_amdgcn_mfma_f32_16x16x32_bf16(fv1, fp_, acc1, 0, 0, 0);
    }

    const float inv = 1.f / l;
    // acc0[r] = O^T[d = 4*grp+r][q = q0+col]; acc1 at d+16
    #pragma unroll
    for (int r = 0; r < 4; ++r) {
        ao[((size_t)b * C_ + h * HD_ + 4 * grp + r) * NPIX + q0 + col] = acc0[r] * inv;
        ao[((size_t)b * C_ + h * HD_ + 16 + 4 * grp + r) * NPIX + q0 + col] = acc1[r] * inv;
    }
}

// ---------------------------------------------------------------------------
extern "C" void kernel_launch(void* const* d_in, const int* in_sizes, int n_in,
                              void* d_out, int out_size, void* d_ws, size_t ws_size,
                              hipStream_t stream) {
    (void)in_sizes; (void)n_in; (void)out_size; (void)ws_size;
    const float* x      = (const float*)d_in[0];
    const float* gamma  = (const float*)d_in[1];
    const float* beta   = (const float*)d_in[2];
    const float* qkv_w  = (const float*)d_in[3];
    const float* qkv_b  = (const float*)d_in[4];
    const float* proj_w = (const float*)d_in[5];
    const float* proj_b = (const float*)d_in[6];
    float* out = (float*)d_out;

    char* ws = (char*)d_ws;
    __bf16* qkvb = (__bf16*)ws;                       // B*768*NPIX bf16 = 12 MB
    __bf16* Qb   = (__bf16*)(ws + 12582912);          // 4 MB
    __bf16* Kb   = (__bf16*)(ws + 16777216);          // 4 MB
    float*  stats= (float*)(ws + 20971520);           // 512 B
    float*  ao   = (float*)(ws + 20972032);           // 8 MB fp32

    gn_stats_kernel<<<dim3(BATCH * NG), dim3(256), 0, stream>>>(x, stats);
    gemm_kernel<0><<<dim3(NPIX / 64, 768 / 64, BATCH), dim3(256), 0, stream>>>(
        qkv_w, qkv_b, x, stats, gamma, beta, nullptr, nullptr, qkvb);
    repack_kernel<<<dim3(NPIX / 64, NH, BATCH), dim3(256), 0, stream>>>(qkvb, Qb, Kb);
    attn_mfma_kernel<<<dim3(NPIX / 64, NH, BATCH), dim3(256), 0, stream>>>(Qb, Kb, qkvb, ao);
    gemm_kernel<1><<<dim3(NPIX / 64, 256 / 64, BATCH), dim3(256), 0, stream>>>(
        proj_w, proj_b, ao, nullptr, nullptr, nullptr, x, out, nullptr);
}

// Round 3
// 236.910 us; speedup vs baseline: 9.0846x; 1.5484x over previous
//
#include <hip/hip_runtime.h>
#include <math.h>

#define C_    256
#define NH    8
#define HD_   32
#define NG    32
#define CPG   8
#define NPIX  4096
#define BATCH 2
#define EPSV  1e-5f
#define SLOG2 0.25503489f   // (1/sqrt(32)) * log2(e)
#define THR   8.0f          // defer-rescale threshold (log2 domain => P <= 256)

typedef __bf16 bf16x8 __attribute__((ext_vector_type(8)));
typedef __bf16 bf16x4 __attribute__((ext_vector_type(4)));
typedef float  f32x4  __attribute__((ext_vector_type(4)));

// ---------------------------------------------------------------------------
// Kernel 1: GroupNorm statistics. One block per (batch, group).
// ---------------------------------------------------------------------------
__global__ __launch_bounds__(256) void gn_stats_kernel(const float* __restrict__ x,
                                                       float* __restrict__ stats) {
    const int blk = blockIdx.x;
    const int b = blk >> 5, g = blk & 31;
    const float* __restrict__ xp = x + ((size_t)(b * C_ + g * CPG)) * NPIX;

    float s = 0.f, ss = 0.f;
    for (int i = threadIdx.x * 4; i < CPG * NPIX; i += 256 * 4) {
        const float4 v = *(const float4*)(xp + i);
        s  += v.x + v.y + v.z + v.w;
        ss += v.x * v.x + v.y * v.y + v.z * v.z + v.w * v.w;
    }
    #pragma unroll
    for (int off = 32; off; off >>= 1) {
        s  += __shfl_down(s, off);
        ss += __shfl_down(ss, off);
    }
    __shared__ float ls[4], lss[4];
    const int wid = threadIdx.x >> 6, lane = threadIdx.x & 63;
    if (lane == 0) { ls[wid] = s; lss[wid] = ss; }
    __syncthreads();
    if (threadIdx.x == 0) {
        float S = 0.f, SS = 0.f;
        #pragma unroll
        for (int w = 0; w < 4; ++w) { S += ls[w]; SS += lss[w]; }
        const float inv_n = 1.0f / (float)(CPG * NPIX);
        const float mean = S * inv_n;
        const float var  = SS * inv_n - mean * mean;
        stats[blk * 2 + 0] = mean;
        stats[blk * 2 + 1] = rsqrtf(var + EPSV);
    }
}

// ---------------------------------------------------------------------------
// Kernel 2: convert qkv_w (768x256) and proj_w (256x256) fp32 -> bf16.
// ---------------------------------------------------------------------------
__global__ __launch_bounds__(256) void wconv_kernel(const float* __restrict__ qw,
                                                    const float* __restrict__ pw,
                                                    __bf16* __restrict__ wbq,
                                                    __bf16* __restrict__ wbp) {
    const int i = (blockIdx.x * 256 + threadIdx.x) * 4;
    const float* src;
    __bf16* dst;
    int off;
    if (i < 768 * 256) { src = qw; dst = wbq; off = i; }
    else { src = pw; dst = wbp; off = i - 768 * 256; }
    const float4 v = *(const float4*)(src + off);
    bf16x4 o;
    o[0] = (__bf16)v.x; o[1] = (__bf16)v.y; o[2] = (__bf16)v.z; o[3] = (__bf16)v.w;
    *(bf16x4*)(dst + off) = o;
}

// ---------------------------------------------------------------------------
// Kernel 3: apply GroupNorm and transpose: Ht[b][n][c] bf16  (64n x 256c tiles)
// ---------------------------------------------------------------------------
__global__ __launch_bounds__(256) void ht_kernel(const float* __restrict__ x,
                                                 const float* __restrict__ stats,
                                                 const float* __restrict__ gamma,
                                                 const float* __restrict__ beta,
                                                 __bf16* __restrict__ Ht) {
    const int b = blockIdx.y;
    const int n0 = blockIdx.x * 64;
    __shared__ __align__(16) __bf16 tile[64][264];  // 264*2B = 33*16B: rows stay 16B-aligned
    const int nn = (threadIdx.x & 15) * 4;
    #pragma unroll
    for (int p = 0; p < 16; ++p) {
        const int c = (threadIdx.x >> 4) + p * 16;
        const float4 v = *(const float4*)(x + ((size_t)(b * C_ + c)) * NPIX + n0 + nn);
        const int g = c >> 3;
        const float mean = stats[(b * NG + g) * 2 + 0];
        const float rstd = stats[(b * NG + g) * 2 + 1];
        const float ga = gamma[c] * rstd;
        const float be = beta[c] - mean * ga;
        tile[nn + 0][c] = (__bf16)(v.x * ga + be);
        tile[nn + 1][c] = (__bf16)(v.y * ga + be);
        tile[nn + 2][c] = (__bf16)(v.z * ga + be);
        tile[nn + 3][c] = (__bf16)(v.w * ga + be);
    }
    __syncthreads();
    #pragma unroll
    for (int p = 0; p < 8; ++p) {
        const int id = p * 256 + threadIdx.x;
        const int row = id >> 5;
        const int ch  = id & 31;
        *(bf16x8*)(Ht + ((size_t)(b * NPIX) + n0 + row) * C_ + ch * 8) =
            *(const bf16x8*)(&tile[row][ch * 8]);
    }
}

// ---------------------------------------------------------------------------
// Kernel 4: QKV GEMM (bf16 MFMA).  C[m=768][n=4096] = W[m][c] * H[c][n] + bias
// Wave tile 64m x 32n, direct global fragments (K=256, fully unrolled).
// Epilogue routes to attention layouts:
//   m<256  -> Qb[bh][n][d] * (scale*log2e)
//   m<512  -> Kb[bh][n][d]
//   else   -> Vb[bh][d][n]
// ---------------------------------------------------------------------------
__global__ __launch_bounds__(256) void qkv_gemm_kernel(const __bf16* __restrict__ wbq,
                                                       const float* __restrict__ bias,
                                                       const __bf16* __restrict__ Ht,
                                                       __bf16* __restrict__ Qb,
                                                       __bf16* __restrict__ Kb,
                                                       __bf16* __restrict__ Vb) {
    const int b = blockIdx.z;
    const int n0 = blockIdx.x * 32;
    const int wave = threadIdx.x >> 6, lane = threadIdx.x & 63;
    const int col = lane & 15, g = lane >> 4;
    const int m0 = blockIdx.y * 256 + wave * 64;
    const __bf16* __restrict__ hp = Ht + (size_t)b * NPIX * C_;

    f32x4 acc[4][2];
    #pragma unroll
    for (int i = 0; i < 4; ++i)
        #pragma unroll
        for (int j = 0; j < 2; ++j) acc[i][j] = (f32x4){0.f, 0.f, 0.f, 0.f};

    #pragma unroll
    for (int c0 = 0; c0 < C_; c0 += 32) {
        bf16x8 la[4], lb[2];
        #pragma unroll
        for (int mb = 0; mb < 4; ++mb)
            la[mb] = *(const bf16x8*)(wbq + (size_t)(m0 + mb * 16 + col) * C_ + c0 + g * 8);
        #pragma unroll
        for (int nb = 0; nb < 2; ++nb)
            lb[nb] = *(const bf16x8*)(hp + (size_t)(n0 + nb * 16 + col) * C_ + c0 + g * 8);
        #pragma unroll
        for (int mb = 0; mb < 4; ++mb)
            #pragma unroll
            for (int nb = 0; nb < 2; ++nb)
                acc[mb][nb] = __builtin_amdgcn_mfma_f32_16x16x32_bf16(la[mb], lb[nb], acc[mb][nb], 0, 0, 0);
    }

    #pragma unroll
    for (int mb = 0; mb < 4; ++mb) {
        const int mbase = m0 + mb * 16 + 4 * g;  // rows mbase..mbase+3
        const float4 b4 = *(const float4*)(bias + mbase);
        const int route = mbase >> 8;
        const int bh = b * NH + ((mbase >> 5) & 7);
        const int d0 = mbase & 31;
        #pragma unroll
        for (int nb = 0; nb < 2; ++nb) {
            const int n = n0 + nb * 16 + col;
            f32x4 v = acc[mb][nb];
            v[0] += b4.x; v[1] += b4.y; v[2] += b4.z; v[3] += b4.w;
            if (route == 0) {
                bf16x4 o;
                #pragma unroll
                for (int r = 0; r < 4; ++r) o[r] = (__bf16)(v[r] * SLOG2);
                *(bf16x4*)(Qb + (((size_t)bh * NPIX + n) << 5) + d0) = o;
            } else if (route == 1) {
                bf16x4 o;
                #pragma unroll
                for (int r = 0; r < 4; ++r) o[r] = (__bf16)v[r];
                *(bf16x4*)(Kb + (((size_t)bh * NPIX + n) << 5) + d0) = o;
            } else {
                #pragma unroll
                for (int r = 0; r < 4; ++r)
                    Vb[((size_t)bh * HD_ + d0 + r) * NPIX + n] = (__bf16)v[r];
            }
        }
    }
}

// ---------------------------------------------------------------------------
// Kernel 5: MFMA flash attention, 32 queries/wave, 32 keys/iter.
// Swapped QK^T (S^T = mfma(K,Q)); softmax in exp2 domain (Q pre-scaled);
// defer-rescale (THR=8); P^T feeds PV directly. Writes O^T[b][n][c] bf16.
// ---------------------------------------------------------------------------
__global__ __launch_bounds__(256) void attn_kernel(const __bf16* __restrict__ Qb,
                                                   const __bf16* __restrict__ Kb,
                                                   const __bf16* __restrict__ Vb,
                                                   __bf16* __restrict__ aot) {
    const int b = blockIdx.z, h = blockIdx.y;
    const int wave = threadIdx.x >> 6, lane = threadIdx.x & 63;
    const int col = lane & 15, g = lane >> 4;
    const int bh = b * NH + h;
    const int q0 = blockIdx.x * 128 + wave * 32;

    const __bf16* __restrict__ qp = Qb + ((size_t)bh * NPIX + q0) * HD_;
    const __bf16* __restrict__ kp = Kb + (size_t)bh * NPIX * HD_;
    const __bf16* __restrict__ vp = Vb + (size_t)bh * HD_ * NPIX;

    const bf16x8 fq0 = *(const bf16x8*)(qp + col * HD_ + g * 8);
    const bf16x8 fq1 = *(const bf16x8*)(qp + (16 + col) * HD_ + g * 8);

    f32x4 acc00 = {0.f,0.f,0.f,0.f}, acc01 = {0.f,0.f,0.f,0.f};
    f32x4 acc10 = {0.f,0.f,0.f,0.f}, acc11 = {0.f,0.f,0.f,0.f};
    float m0 = -3.0e38f, m1 = -3.0e38f, l0 = 0.f, l1 = 0.f;

    #pragma unroll 2
    for (int k0 = 0; k0 < NPIX; k0 += 32) {
        const __bf16* kt = kp + (size_t)k0 * HD_;
        const bf16x8 fk0 = *(const bf16x8*)(kt + col * HD_ + g * 8);
        const bf16x8 fk1 = *(const bf16x8*)(kt + (16 + col) * HD_ + g * 8);
        // V fragment loads issued early (independent of QK/softmax chain)
        const __bf16* vt0 = vp + (size_t)col * NPIX + k0 + 4 * g;
        const __bf16* vt1 = vp + (size_t)(16 + col) * NPIX + k0 + 4 * g;
        const bf16x4 va0 = *(const bf16x4*)(vt0);
        const bf16x4 va1 = *(const bf16x4*)(vt0 + 16);
        const bf16x4 vb0 = *(const bf16x4*)(vt1);
        const bf16x4 vb1 = *(const bf16x4*)(vt1 + 16);

        const f32x4 z = {0.f, 0.f, 0.f, 0.f};
        f32x4 s00 = __builtin_amdgcn_mfma_f32_16x16x32_bf16(fk0, fq0, z, 0, 0, 0);
        f32x4 s10 = __builtin_amdgcn_mfma_f32_16x16x32_bf16(fk1, fq0, z, 0, 0, 0);
        f32x4 s01 = __builtin_amdgcn_mfma_f32_16x16x32_bf16(fk0, fq1, z, 0, 0, 0);
        f32x4 s11 = __builtin_amdgcn_mfma_f32_16x16x32_bf16(fk1, fq1, z, 0, 0, 0);

        float pm0 = fmaxf(fmaxf(fmaxf(s00[0], s00[1]), fmaxf(s00[2], s00[3])),
                          fmaxf(fmaxf(s10[0], s10[1]), fmaxf(s10[2], s10[3])));
        float pm1 = fmaxf(fmaxf(fmaxf(s01[0], s01[1]), fmaxf(s01[2], s01[3])),
                          fmaxf(fmaxf(s11[0], s11[1]), fmaxf(s11[2], s11[3])));
        pm0 = fmaxf(pm0, __shfl_xor(pm0, 16));
        pm0 = fmaxf(pm0, __shfl_xor(pm0, 32));
        pm1 = fmaxf(pm1, __shfl_xor(pm1, 16));
        pm1 = fmaxf(pm1, __shfl_xor(pm1, 32));

        const bool need = (pm0 > m0 + THR) || (pm1 > m1 + THR);
        if (__any(need)) {
            const float mn0 = fmaxf(m0, pm0), mn1 = fmaxf(m1, pm1);
            const float cf0 = exp2f(m0 - mn0), cf1 = exp2f(m1 - mn1);
            l0 *= cf0; l1 *= cf1;
            #pragma unroll
            for (int r = 0; r < 4; ++r) {
                acc00[r] *= cf0; acc01[r] *= cf0;
                acc10[r] *= cf1; acc11[r] *= cf1;
            }
            m0 = mn0; m1 = mn1;
        }

        float p0[8], p1[8];
        #pragma unroll
        for (int r = 0; r < 4; ++r) {
            p0[r] = exp2f(s00[r] - m0); p0[4 + r] = exp2f(s10[r] - m0);
            p1[r] = exp2f(s01[r] - m1); p1[4 + r] = exp2f(s11[r] - m1);
        }
        float ls0 = 0.f, ls1 = 0.f;
        #pragma unroll
        for (int j = 0; j < 8; ++j) { ls0 += p0[j]; ls1 += p1[j]; }
        ls0 += __shfl_xor(ls0, 16); ls0 += __shfl_xor(ls0, 32);
        ls1 += __shfl_xor(ls1, 16); ls1 += __shfl_xor(ls1, 32);
        l0 += ls0; l1 += ls1;

        bf16x8 fp0, fp1, fv0, fv1;
        #pragma unroll
        for (int j = 0; j < 8; ++j) { fp0[j] = (__bf16)p0[j]; fp1[j] = (__bf16)p1[j]; }
        #pragma unroll
        for (int j = 0; j < 4; ++j) {
            fv0[j] = va0[j]; fv0[4 + j] = va1[j];
            fv1[j] = vb0[j]; fv1[4 + j] = vb1[j];
        }
        acc00 = __builtin_amdgcn_mfma_f32_16x16x32_bf16(fv0, fp0, acc00, 0, 0, 0);
        acc01 = __builtin_amdgcn_mfma_f32_16x16x32_bf16(fv1, fp0, acc01, 0, 0, 0);
        acc10 = __builtin_amdgcn_mfma_f32_16x16x32_bf16(fv0, fp1, acc10, 0, 0, 0);
        acc11 = __builtin_amdgcn_mfma_f32_16x16x32_bf16(fv1, fp1, acc11, 0, 0, 0);
    }

    const float inv0 = 1.0f / l0;
    const float inv1 = 1.0f / l1;
    const int cb = h * HD_ + 4 * g;
    {
        __bf16* op = aot + ((size_t)(b * NPIX) + q0 + col) * C_ + cb;
        bf16x4 o0, o1;
        #pragma unroll
        for (int r = 0; r < 4; ++r) { o0[r] = (__bf16)(acc00[r] * inv0); o1[r] = (__bf16)(acc01[r] * inv0); }
        *(bf16x4*)(op) = o0;
        *(bf16x4*)(op + 16) = o1;
    }
    {
        __bf16* op = aot + ((size_t)(b * NPIX) + q0 + 16 + col) * C_ + cb;
        bf16x4 o0, o1;
        #pragma unroll
        for (int r = 0; r < 4; ++r) { o0[r] = (__bf16)(acc10[r] * inv1); o1[r] = (__bf16)(acc11[r] * inv1); }
        *(bf16x4*)(op) = o0;
        *(bf16x4*)(op + 16) = o1;
    }
}

// ---------------------------------------------------------------------------
// Kernel 6: proj GEMM (bf16 MFMA) + bias + residual, fp32 out.
// C[m=256][n=4096] = P[m][c] * O[c][n];  O^T given as aot[n][c].
// Wave tile 32m x 32n; block = 2x2 waves (64m x 64n).
// ---------------------------------------------------------------------------
__global__ __launch_bounds__(256) void proj_gemm_kernel(const __bf16* __restrict__ wbp,
                                                        const float* __restrict__ bias,
                                                        const __bf16* __restrict__ aot,
                                                        const float* __restrict__ x,
                                                        float* __restrict__ out) {
    const int b = blockIdx.z;
    const int wave = threadIdx.x >> 6, lane = threadIdx.x & 63;
    const int col = lane & 15, g = lane >> 4;
    const int n0 = blockIdx.x * 64 + (wave & 1) * 32;
    const int m0 = blockIdx.y * 64 + (wave >> 1) * 32;
    const __bf16* __restrict__ ap = aot + (size_t)b * NPIX * C_;

    f32x4 acc[2][2];
    #pragma unroll
    for (int i = 0; i < 2; ++i)
        #pragma unroll
        for (int j = 0; j < 2; ++j) acc[i][j] = (f32x4){0.f, 0.f, 0.f, 0.f};

    #pragma unroll
    for (int c0 = 0; c0 < C_; c0 += 32) {
        bf16x8 la[2], lb[2];
        #pragma unroll
        for (int mb = 0; mb < 2; ++mb)
            la[mb] = *(const bf16x8*)(wbp + (size_t)(m0 + mb * 16 + col) * C_ + c0 + g * 8);
        #pragma unroll
        for (int nb = 0; nb < 2; ++nb)
            lb[nb] = *(const bf16x8*)(ap + (size_t)(n0 + nb * 16 + col) * C_ + c0 + g * 8);
        #pragma unroll
        for (int mb = 0; mb < 2; ++mb)
            #pragma unroll
            for (int nb = 0; nb < 2; ++nb)
                acc[mb][nb] = __builtin_amdgcn_mfma_f32_16x16x32_bf16(la[mb], lb[nb], acc[mb][nb], 0, 0, 0);
    }

    #pragma unroll
    for (int mb = 0; mb < 2; ++mb) {
        const int mbase = m0 + mb * 16 + 4 * g;
        const float4 b4 = *(const float4*)(bias + mbase);
        const float bias_r[4] = {b4.x, b4.y, b4.z, b4.w};
        #pragma unroll
        for (int nb = 0; nb < 2; ++nb) {
            const int n = n0 + nb * 16 + col;
            #pragma unroll
            for (int r = 0; r < 4; ++r) {
                const size_t idx = ((size_t)(b * C_ + mbase + r)) * NPIX + n;
                out[idx] = acc[mb][nb][r] + bias_r[r] + x[idx];
            }
        }
    }
}

// ---------------------------------------------------------------------------
extern "C" void kernel_launch(void* const* d_in, const int* in_sizes, int n_in,
                              void* d_out, int out_size, void* d_ws, size_t ws_size,
                              hipStream_t stream) {
    (void)in_sizes; (void)n_in; (void)out_size; (void)ws_size;
    const float* x      = (const float*)d_in[0];
    const float* gamma  = (const float*)d_in[1];
    const float* beta   = (const float*)d_in[2];
    const float* qkv_w  = (const float*)d_in[3];
    const float* qkv_b  = (const float*)d_in[4];
    const float* proj_w = (const float*)d_in[5];
    const float* proj_b = (const float*)d_in[6];
    float* out = (float*)d_out;

    char* ws = (char*)d_ws;
    __bf16* wbq  = (__bf16*)(ws);              // 768*256*2   = 384 KB
    __bf16* wbp  = (__bf16*)(ws + 0x60000);    // 256*256*2   = 128 KB
    float*  stats= (float*) (ws + 0x80000);    // 512 B
    __bf16* Ht   = (__bf16*)(ws + 0x100000);   // 2*4096*256*2 = 4 MB
    __bf16* Qb   = (__bf16*)(ws + 0x500000);   // 4 MB
    __bf16* Kb   = (__bf16*)(ws + 0x900000);   // 4 MB
    __bf16* Vb   = (__bf16*)(ws + 0xD00000);   // 4 MB
    __bf16* aot  = (__bf16*)(ws + 0x1100000);  // 4 MB

    gn_stats_kernel<<<dim3(BATCH * NG), dim3(256), 0, stream>>>(x, stats);
    wconv_kernel<<<dim3(256), dim3(256), 0, stream>>>(qkv_w, proj_w, wbq, wbp);
    ht_kernel<<<dim3(NPIX / 64, BATCH), dim3(256), 0, stream>>>(x, stats, gamma, beta, Ht);
    qkv_gemm_kernel<<<dim3(NPIX / 32, 3, BATCH), dim3(256), 0, stream>>>(wbq, qkv_b, Ht, Qb, Kb, Vb);
    attn_kernel<<<dim3(NPIX / 128, NH, BATCH), dim3(256), 0, stream>>>(Qb, Kb, Vb, aot);
    proj_gemm_kernel<<<dim3(NPIX / 64, C_ / 64, BATCH), dim3(256), 0, stream>>>(wbp, proj_b, aot, x, out);
}